// Round 2
// baseline (7168.288 us; speedup 1.0000x reference)
//
#include <hip/hip_runtime.h>

#define NH    16
#define DK    64
#define DIM   1024
#define BATCH 2
#define SEQ   2048
#define MROWS (BATCH*SEQ)   // 4096

typedef unsigned short bfraw;
typedef __attribute__((ext_vector_type(8))) __bf16 bf16x8;
typedef __attribute__((ext_vector_type(8))) unsigned short u16x8;
typedef __attribute__((ext_vector_type(4))) float f32x4;

__device__ __forceinline__ float bf2f(bfraw u) {
    union { unsigned int i; float f; } x; x.i = ((unsigned int)u) << 16; return x.f;
}
__device__ __forceinline__ bfraw f2bf(float f) {
    union { float f; unsigned int i; } x; x.f = f;
    unsigned int r = x.i + 0x7FFFu + ((x.i >> 16) & 1u);   // RNE
    return (bfraw)(r >> 16);
}

// ---------------- block reduction (256 threads = 4 waves) ----------------
__device__ __forceinline__ float block_reduce(float val, float* rbuf, int op /*0=max,1=sum*/) {
    const int lane = threadIdx.x & 63;
    const int wave = threadIdx.x >> 6;
    #pragma unroll
    for (int off = 32; off; off >>= 1) {
        float o = __shfl_xor(val, off, 64);
        val = op ? (val + o) : fmaxf(val, o);
    }
    if (lane == 0) rbuf[wave] = val;
    __syncthreads();
    float r = op ? (rbuf[0] + rbuf[1] + rbuf[2] + rbuf[3])
                 : fmaxf(fmaxf(rbuf[0], rbuf[1]), fmaxf(rbuf[2], rbuf[3]));
    __syncthreads();
    return r;
}

// ---------------- 64x64 MFMA GEMM tile: C = A[M,1024] * W[N,1024]^T ----------------
// A is fp32 (A_BF16=false) or bf16-raw (A_BF16=true); W is fp32. Both converted
// to bf16 in-register before LDS staging. block = 256 threads (4 waves).
// gfx950 16x16x32 bf16 layouts: A-op A[m=lane&15][k=quad*8+j];
// B-op B[k=quad*8+j][n=lane&15]; C/D row=(lane>>4)*4+reg, col=lane&15.
template<bool A_BF16>
__device__ __forceinline__ void gemm64x64(const void* __restrict__ Aq,
                                          const float* __restrict__ W,
                                          int m0, int n0, f32x4 acc[4]) {
    __shared__ __align__(16) bfraw As[64 * 32];
    __shared__ __align__(16) bfraw Bs[64 * 32];
    const int tid  = threadIdx.x;
    const int wave = tid >> 6;
    const int lane = tid & 63;
    const int lrow = lane & 15;
    const int quad = lane >> 4;
    const int ldr  = tid >> 2;          // 0..63 (tile row to load)
    const int ldc  = (tid & 3) << 3;    // 0,8,16,24 (k offset)

    #pragma unroll
    for (int j = 0; j < 4; j++) { f32x4 z = {0.f, 0.f, 0.f, 0.f}; acc[j] = z; }

    for (int k0 = 0; k0 < DIM; k0 += 32) {
        u16x8 av, bv;
        if (A_BF16) {
            av = *(const u16x8*)((const bfraw*)Aq + (m0 + ldr) * DIM + k0 + ldc);
        } else {
            const float* ap = (const float*)Aq + (m0 + ldr) * DIM + k0 + ldc;
            f32x4 a0 = *(const f32x4*)ap;
            f32x4 a1 = *(const f32x4*)(ap + 4);
            #pragma unroll
            for (int j = 0; j < 4; j++) { av[j] = f2bf(a0[j]); av[4 + j] = f2bf(a1[j]); }
        }
        {
            const float* wp = W + (n0 + ldr) * DIM + k0 + ldc;
            f32x4 b0 = *(const f32x4*)wp;
            f32x4 b1 = *(const f32x4*)(wp + 4);
            #pragma unroll
            for (int j = 0; j < 4; j++) { bv[j] = f2bf(b0[j]); bv[4 + j] = f2bf(b1[j]); }
        }
        __syncthreads();                        // previous iter's LDS reads done
        *(u16x8*)&As[ldr * 32 + ldc] = av;
        *(u16x8*)&Bs[ldr * 32 + ldc] = bv;
        __syncthreads();
        bf16x8 af = *(const bf16x8*)&As[(wave * 16 + lrow) * 32 + quad * 8];
        #pragma unroll
        for (int j = 0; j < 4; j++) {
            bf16x8 bfg = *(const bf16x8*)&Bs[(j * 16 + lrow) * 32 + quad * 8];
            acc[j] = __builtin_amdgcn_mfma_f32_16x16x32_bf16(af, bfg, acc[j], 0, 0, 0);
        }
    }
}

// ---------------- QKV projection: out layout [B,H,S,K] bf16 ----------------
__global__ __launch_bounds__(256) void qkv_gemm(
        const float* __restrict__ Xq, const float* __restrict__ Xk, const float* __restrict__ Xv,
        const float* __restrict__ Wq, const float* __restrict__ Wk, const float* __restrict__ Wv,
        bfraw* __restrict__ Qp, bfraw* __restrict__ Kp, bfraw* __restrict__ Vp) {
    const int which = blockIdx.z;
    const float* A = (which == 0) ? Xq : (which == 1) ? Xk : Xv;
    const float* W = (which == 0) ? Wq : (which == 1) ? Wk : Wv;
    bfraw*       O = (which == 0) ? Qp : (which == 1) ? Kp : Vp;
    const int m0 = blockIdx.y * 64, n0 = blockIdx.x * 64;
    f32x4 acc[4];
    gemm64x64<false>(A, W, m0, n0, acc);
    const int lane = threadIdx.x & 63, wave = threadIdx.x >> 6;
    const int lrow = lane & 15, quad = lane >> 4;
    #pragma unroll
    for (int j = 0; j < 4; j++)
        #pragma unroll
        for (int i = 0; i < 4; i++) {
            int m = m0 + wave * 16 + quad * 4 + i;
            int n = n0 + j * 16 + lrow;
            int b = m >> 11, s = m & (SEQ - 1), h = n >> 6, kk = n & (DK - 1);
            O[(((b * NH + h) * SEQ) + s) * DK + kk] = f2bf(acc[j][i]);
        }
}

// ---------------- attention: one block per (b,h,q) row ----------------
__global__ __launch_bounds__(256) void attn_kernel(
        const bfraw* __restrict__ Qp, const bfraw* __restrict__ Kp, const bfraw* __restrict__ Vp,
        const int* __restrict__ mask, bfraw* __restrict__ Ctx) {
    __shared__ float sc[SEQ];          // 8 KB
    __shared__ float qv[DK];
    __shared__ float part[4][DK];
    __shared__ float rbuf[4];
    const int q = blockIdx.x, h = blockIdx.y, b = blockIdx.z;
    const int tid = threadIdx.x;
    const int base = ((b * NH + h) * SEQ) * DK;

    if (tid < DK) qv[tid] = bf2f(Qp[base + q * DK + tid]);
    __syncthreads();

    const int* mrow = mask + b * SEQ;
    float lmax = -3.0e38f;
    #pragma unroll
    for (int i = 0; i < 8; i++) {
        int s = tid + (i << 8);
        const u16x8* kr = (const u16x8*)(Kp + base + s * DK);
        float d = 0.f;
        #pragma unroll
        for (int k8 = 0; k8 < 8; k8++) {
            u16x8 kv = kr[k8];
            #pragma unroll
            for (int jj = 0; jj < 8; jj++) d += qv[k8 * 8 + jj] * bf2f(kv[jj]);
        }
        // attend only where mask==1 AND s>q; NEG=-1e12 swallows the score in fp32,
        // so masked entries are exactly -1e12f -> all-masked rows give uniform softmax,
        // exactly matching the fp32 reference.
        bool valid = (s > q) && (mrow[s] != 0);
        float v = valid ? d * 0.125f : -1e12f;
        sc[s] = v;
        lmax = fmaxf(lmax, v);
    }
    float gmax = block_reduce(lmax, rbuf, 0);

    float lsum = 0.f;
    #pragma unroll
    for (int i = 0; i < 8; i++) {
        int s = tid + (i << 8);
        float e = __expf(sc[s] - gmax);
        sc[s] = e;
        lsum += e;
    }
    float gsum = block_reduce(lsum, rbuf, 1);   // includes barrier: all sc[] now exp'd

    const int kk = tid & 63, g = tid >> 6;
    float a0 = 0.f;
    for (int s = g; s < SEQ; s += 4)
        a0 += sc[s] * bf2f(Vp[base + s * DK + kk]);
    part[g][kk] = a0;
    __syncthreads();
    if (tid < DK) {
        float r = (part[0][tid] + part[1][tid] + part[2][tid] + part[3][tid]) * (1.0f / gsum);
        Ctx[(b * SEQ + q) * DIM + h * DK + tid] = f2bf(r);   // [B,S,H*K] layout
    }
}

// ---------------- output projection: C fp32 = Ctx[4096,1024](bf16) * Wo[1024,1024]^T ----------------
__global__ __launch_bounds__(256) void out_gemm(
        const bfraw* __restrict__ Ctx, const float* __restrict__ Wo, float* __restrict__ C) {
    const int m0 = blockIdx.y * 64, n0 = blockIdx.x * 64;
    f32x4 acc[4];
    gemm64x64<true>(Ctx, Wo, m0, n0, acc);
    const int lane = threadIdx.x & 63, wave = threadIdx.x >> 6;
    const int lrow = lane & 15, quad = lane >> 4;
    #pragma unroll
    for (int j = 0; j < 4; j++)
        #pragma unroll
        for (int i = 0; i < 4; i++) {
            int m = m0 + wave * 16 + quad * 4 + i;
            int n = n0 + j * 16 + lrow;
            C[m * DIM + n] = acc[j][i];
        }
}

// ---------------- residual + LayerNorm (all fp32) ----------------
__global__ __launch_bounds__(256) void ln_kernel(
        const float* __restrict__ C, const float* __restrict__ Xq,
        const float* __restrict__ gamma, const float* __restrict__ beta,
        float* __restrict__ out) {
    __shared__ float rbuf[4];
    const int m = blockIdx.x, tid = threadIdx.x;
    const float* crow = C + m * DIM;
    const float* xrow = Xq + m * DIM;
    float v[4]; float s = 0.f, s2 = 0.f;
    #pragma unroll
    for (int i = 0; i < 4; i++) {
        int d = tid + (i << 8);
        float x = crow[d] + xrow[d];
        v[i] = x; s += x; s2 += x * x;
    }
    float S  = block_reduce(s,  rbuf, 1);
    float S2 = block_reduce(s2, rbuf, 1);
    float mu  = S * (1.0f / DIM);
    float var = S2 * (1.0f / DIM) - mu * mu;
    float rstd = rsqrtf(var + 1e-5f);
    #pragma unroll
    for (int i = 0; i < 4; i++) {
        int d = tid + (i << 8);
        out[m * DIM + d] = (v[i] - mu) * rstd * gamma[d] + beta[d];
    }
}

extern "C" void kernel_launch(void* const* d_in, const int* in_sizes, int n_in,
                              void* d_out, int out_size, void* d_ws, size_t ws_size,
                              hipStream_t stream) {
    const float* Xq    = (const float*)d_in[0];
    const float* Xk    = (const float*)d_in[1];
    const float* Xv    = (const float*)d_in[2];
    const int*   mask  = (const int*)  d_in[3];
    const float* Wq    = (const float*)d_in[4];
    const float* Wk    = (const float*)d_in[5];
    const float* Wv    = (const float*)d_in[6];
    const float* Wo    = (const float*)d_in[7];
    const float* gamma = (const float*)d_in[8];
    const float* beta  = (const float*)d_in[9];
    float* out = (float*)d_out;

    // ws layout (32 MB): Qp[0,8M) Kp[8,16M) Vp[16,24M) Ctx[24,32M) all bf16;
    // C fp32 overlaps [0,16M) = Qp+Kp, which are dead once attention has run.
    char* ws = (char*)d_ws;
    bfraw* Qp  = (bfraw*)(ws);
    bfraw* Kp  = (bfraw*)(ws + (8u  << 20));
    bfraw* Vp  = (bfraw*)(ws + (16u << 20));
    bfraw* Ctx = (bfraw*)(ws + (24u << 20));
    float* C   = (float*)(ws);

    dim3 blk(256);
    qkv_gemm <<<dim3(DIM / 64, MROWS / 64, 3), blk, 0, stream>>>(Xq, Xk, Xv, Wq, Wk, Wv, Qp, Kp, Vp);
    attn_kernel<<<dim3(SEQ, NH, BATCH),        blk, 0, stream>>>(Qp, Kp, Vp, mask, Ctx);
    out_gemm <<<dim3(DIM / 64, MROWS / 64),    blk, 0, stream>>>(Ctx, Wo, C);
    ln_kernel<<<dim3(MROWS),                   blk, 0, stream>>>(C, Xq, gamma, beta, out);
}

// Round 3
// 352.647 us; speedup vs baseline: 20.3271x; 20.3271x over previous
//
#include <hip/hip_runtime.h>

#define NH    16
#define DK    64
#define DIM   1024
#define BATCH 2
#define SEQ   2048
#define MROWS (BATCH*SEQ)   // 4096
#define KT    64            // key-tile for flash attention

typedef unsigned short bfraw;
typedef __attribute__((ext_vector_type(8))) __bf16 bf16x8;
typedef __attribute__((ext_vector_type(8))) unsigned short u16x8;
typedef __attribute__((ext_vector_type(4))) float f32x4;

__device__ __forceinline__ float bf2f(bfraw u) {
    union { unsigned int i; float f; } x; x.i = ((unsigned int)u) << 16; return x.f;
}
__device__ __forceinline__ bfraw f2bf(float f) {
    union { float f; unsigned int i; } x; x.f = f;
    unsigned int r = x.i + 0x7FFFu + ((x.i >> 16) & 1u);   // RNE
    return (bfraw)(r >> 16);
}

// ---------------- block reduction (256 threads = 4 waves) ----------------
__device__ __forceinline__ float block_reduce(float val, float* rbuf, int op /*0=max,1=sum*/) {
    const int lane = threadIdx.x & 63;
    const int wave = threadIdx.x >> 6;
    #pragma unroll
    for (int off = 32; off; off >>= 1) {
        float o = __shfl_xor(val, off, 64);
        val = op ? (val + o) : fmaxf(val, o);
    }
    if (lane == 0) rbuf[wave] = val;
    __syncthreads();
    float r = op ? (rbuf[0] + rbuf[1] + rbuf[2] + rbuf[3])
                 : fmaxf(fmaxf(rbuf[0], rbuf[1]), fmaxf(rbuf[2], rbuf[3]));
    __syncthreads();
    return r;
}

// ---------------- 64x64 MFMA GEMM tile: C = A[M,1024] * W[N,1024]^T ----------------
template<bool A_BF16>
__device__ __forceinline__ void gemm64x64(const void* __restrict__ Aq,
                                          const float* __restrict__ W,
                                          int m0, int n0, f32x4 acc[4]) {
    __shared__ __align__(16) bfraw As[64 * 32];
    __shared__ __align__(16) bfraw Bs[64 * 32];
    const int tid  = threadIdx.x;
    const int wave = tid >> 6;
    const int lane = tid & 63;
    const int lrow = lane & 15;
    const int quad = lane >> 4;
    const int ldr  = tid >> 2;          // 0..63 (tile row to load)
    const int ldc  = (tid & 3) << 3;    // 0,8,16,24 (k offset)

    #pragma unroll
    for (int j = 0; j < 4; j++) { f32x4 z = {0.f, 0.f, 0.f, 0.f}; acc[j] = z; }

    for (int k0 = 0; k0 < DIM; k0 += 32) {
        u16x8 av, bv;
        if (A_BF16) {
            av = *(const u16x8*)((const bfraw*)Aq + (m0 + ldr) * DIM + k0 + ldc);
        } else {
            const float* ap = (const float*)Aq + (m0 + ldr) * DIM + k0 + ldc;
            f32x4 a0 = *(const f32x4*)ap;
            f32x4 a1 = *(const f32x4*)(ap + 4);
            #pragma unroll
            for (int j = 0; j < 4; j++) { av[j] = f2bf(a0[j]); av[4 + j] = f2bf(a1[j]); }
        }
        {
            const float* wp = W + (n0 + ldr) * DIM + k0 + ldc;
            f32x4 b0 = *(const f32x4*)wp;
            f32x4 b1 = *(const f32x4*)(wp + 4);
            #pragma unroll
            for (int j = 0; j < 4; j++) { bv[j] = f2bf(b0[j]); bv[4 + j] = f2bf(b1[j]); }
        }
        __syncthreads();
        *(u16x8*)&As[ldr * 32 + ldc] = av;
        *(u16x8*)&Bs[ldr * 32 + ldc] = bv;
        __syncthreads();
        bf16x8 af = *(const bf16x8*)&As[(wave * 16 + lrow) * 32 + quad * 8];
        #pragma unroll
        for (int j = 0; j < 4; j++) {
            bf16x8 bfg = *(const bf16x8*)&Bs[(j * 16 + lrow) * 32 + quad * 8];
            acc[j] = __builtin_amdgcn_mfma_f32_16x16x32_bf16(af, bfg, acc[j], 0, 0, 0);
        }
    }
}

// ---------------- QKV projection ----------------
// Q,K out: [B,H,S,DK]; V out TRANSPOSED: [B,H,DK,S] (so flash PV B-frags read contiguous)
__global__ __launch_bounds__(256) void qkv_gemm(
        const float* __restrict__ Xq, const float* __restrict__ Xk, const float* __restrict__ Xv,
        const float* __restrict__ Wq, const float* __restrict__ Wk, const float* __restrict__ Wv,
        bfraw* __restrict__ Qp, bfraw* __restrict__ Kp, bfraw* __restrict__ Vt) {
    const int which = blockIdx.z;
    const float* A = (which == 0) ? Xq : (which == 1) ? Xk : Xv;
    const float* W = (which == 0) ? Wq : (which == 1) ? Wk : Wv;
    bfraw*       O = (which == 0) ? Qp : (which == 1) ? Kp : Vt;
    const int m0 = blockIdx.y * 64, n0 = blockIdx.x * 64;
    f32x4 acc[4];
    gemm64x64<false>(A, W, m0, n0, acc);
    const int lane = threadIdx.x & 63, wave = threadIdx.x >> 6;
    const int lrow = lane & 15, quad = lane >> 4;
    #pragma unroll
    for (int j = 0; j < 4; j++)
        #pragma unroll
        for (int i = 0; i < 4; i++) {
            int m = m0 + wave * 16 + quad * 4 + i;
            int n = n0 + j * 16 + lrow;
            int b = m >> 11, s = m & (SEQ - 1), h = n >> 6, kk = n & (DK - 1);
            bfraw v = f2bf(acc[j][i]);
            if (which == 2) O[(((b * NH + h) * DK) + kk) * SEQ + s] = v;
            else            O[(((b * NH + h) * SEQ) + s) * DK + kk] = v;
        }
}

// ---------------- flash MFMA attention ----------------
// grid (SEQ/64, NH, BATCH), block 256 (4 waves). Wave w owns q rows [qt*64+16w, +16).
// Iterates 32 key-tiles of KT=64; QK^T and PV on MFMA; online softmax fp32.
// Masked score = exactly -1e12f: alpha underflows to 0 once a valid score exists;
// fully-masked rows keep m=-1e12, p=1 each -> uniform 1/2048, matching the fp32 ref.
__global__ __launch_bounds__(256) void attn_flash(
        const bfraw* __restrict__ Qp, const bfraw* __restrict__ Kp, const bfraw* __restrict__ Vt,
        const int* __restrict__ mask, bfraw* __restrict__ Ctx) {
    __shared__ __align__(16) bfraw Ks[64 * 72];        // K-tile [s][k], pad 8
    __shared__ __align__(16) bfraw Vs[64 * 72];        // V-tile transposed [d][s], pad 8
    __shared__ __align__(16) bfraw Pw[4][16 * 72];     // per-wave P [q][s], pad 8
    __shared__ unsigned short Mk[SEQ];
    const int qt = blockIdx.x, h = blockIdx.y, b = blockIdx.z;
    const int tid  = threadIdx.x;
    const int wave = tid >> 6, lane = tid & 63;
    const int lrow = lane & 15, quad = lane >> 4;
    const int baseK = ((b * NH + h) * SEQ) * DK;       // Q,K: [B,H,S,DK]
    const int baseV = ((b * NH + h) * DK) * SEQ;       // V:   [B,H,DK,S]
    const int qbase = qt * 64 + wave * 16;
    const int ldr = tid >> 2, ldc = (tid & 3) << 4;    // staging: row 0..63, col {0,16,32,48}

    for (int i = tid; i < SEQ; i += 256) Mk[i] = (unsigned short)(mask[b * SEQ + i] != 0);

    bf16x8 qf[2];
    qf[0] = *(const bf16x8*)(Qp + baseK + (qbase + lrow) * DK + quad * 8);
    qf[1] = *(const bf16x8*)(Qp + baseK + (qbase + lrow) * DK + 32 + quad * 8);

    f32x4 O[4];
    float m_i[4], l_i[4];
    #pragma unroll
    for (int n = 0; n < 4; n++) { f32x4 z = {0.f, 0.f, 0.f, 0.f}; O[n] = z; }
    #pragma unroll
    for (int i = 0; i < 4; i++) { m_i[i] = -3.0e38f; l_i[i] = 0.f; }

    const int qrow = qbase + quad * 4;                 // + i = this lane's C/D rows

    for (int kt0 = 0; kt0 < SEQ; kt0 += KT) {
        u16x8 k0 = *(const u16x8*)(Kp + baseK + (kt0 + ldr) * DK + ldc);
        u16x8 k1 = *(const u16x8*)(Kp + baseK + (kt0 + ldr) * DK + ldc + 8);
        u16x8 v0 = *(const u16x8*)(Vt + baseV + ldr * SEQ + kt0 + ldc);
        u16x8 v1 = *(const u16x8*)(Vt + baseV + ldr * SEQ + kt0 + ldc + 8);
        __syncthreads();                               // prior iter's LDS reads done
        *(u16x8*)&Ks[ldr * 72 + ldc]     = k0;
        *(u16x8*)&Ks[ldr * 72 + ldc + 8] = k1;
        *(u16x8*)&Vs[ldr * 72 + ldc]     = v0;
        *(u16x8*)&Vs[ldr * 72 + ldc + 8] = v1;
        __syncthreads();

        // S = Q K^T (16 q-rows x 64 s-cols per wave)
        f32x4 S[4];
        #pragma unroll
        for (int n = 0; n < 4; n++) {
            f32x4 z = {0.f, 0.f, 0.f, 0.f}; S[n] = z;
            #pragma unroll
            for (int ks = 0; ks < 2; ks++) {
                bf16x8 kb = *(const bf16x8*)&Ks[(n * 16 + lrow) * 72 + ks * 32 + quad * 8];
                S[n] = __builtin_amdgcn_mfma_f32_16x16x32_bf16(qf[ks], kb, S[n], 0, 0, 0);
            }
        }

        // mask + scale (exactly the reference's -1e12 semantics)
        float sc[4][4];
        #pragma unroll
        for (int n = 0; n < 4; n++) {
            int s = kt0 + n * 16 + lrow;
            bool mk = (Mk[s] != 0);
            #pragma unroll
            for (int i = 0; i < 4; i++) {
                bool valid = mk && (s > qrow + i);
                sc[n][i] = valid ? S[n][i] * 0.125f : -1e12f;
            }
        }

        // online softmax update (row stats across the 16 lanes of this quad-group)
        float alpha[4], p[4][4];
        #pragma unroll
        for (int i = 0; i < 4; i++) {
            float t = fmaxf(fmaxf(sc[0][i], sc[1][i]), fmaxf(sc[2][i], sc[3][i]));
            #pragma unroll
            for (int off = 1; off < 16; off <<= 1) t = fmaxf(t, __shfl_xor(t, off, 64));
            float mn = fmaxf(m_i[i], t);
            alpha[i] = __expf(m_i[i] - mn);
            m_i[i] = mn;
        }
        #pragma unroll
        for (int n = 0; n < 4; n++)
            #pragma unroll
            for (int i = 0; i < 4; i++) p[n][i] = __expf(sc[n][i] - m_i[i]);
        #pragma unroll
        for (int i = 0; i < 4; i++) {
            float r = (p[0][i] + p[1][i]) + (p[2][i] + p[3][i]);
            #pragma unroll
            for (int off = 1; off < 16; off <<= 1) r += __shfl_xor(r, off, 64);
            l_i[i] = l_i[i] * alpha[i] + r;
        }

        // P: C/D layout -> LDS -> A-operand layout (per-wave region, no barrier needed)
        #pragma unroll
        for (int n = 0; n < 4; n++)
            #pragma unroll
            for (int i = 0; i < 4; i++)
                Pw[wave][(quad * 4 + i) * 72 + n * 16 + lrow] = f2bf(p[n][i]);

        #pragma unroll
        for (int n = 0; n < 4; n++)
            #pragma unroll
            for (int i = 0; i < 4; i++) O[n][i] *= alpha[i];

        bf16x8 pa0 = *(const bf16x8*)&Pw[wave][lrow * 72 + quad * 8];
        bf16x8 pa1 = *(const bf16x8*)&Pw[wave][lrow * 72 + 32 + quad * 8];
        #pragma unroll
        for (int n = 0; n < 4; n++) {
            #pragma unroll
            for (int ks = 0; ks < 2; ks++) {
                bf16x8 vb = *(const bf16x8*)&Vs[(n * 16 + lrow) * 72 + ks * 32 + quad * 8];
                O[n] = __builtin_amdgcn_mfma_f32_16x16x32_bf16(ks ? pa1 : pa0, vb, O[n], 0, 0, 0);
            }
        }
    }

    float inv[4];
    #pragma unroll
    for (int i = 0; i < 4; i++) inv[i] = 1.0f / l_i[i];
    #pragma unroll
    for (int n = 0; n < 4; n++)
        #pragma unroll
        for (int i = 0; i < 4; i++)
            Ctx[(b * SEQ + qrow + i) * DIM + h * DK + n * 16 + lrow] = f2bf(O[n][i] * inv[i]);
}

// ---------------- output projection: C fp32 = Ctx[4096,1024](bf16) * Wo[1024,1024]^T ----------------
__global__ __launch_bounds__(256) void out_gemm(
        const bfraw* __restrict__ Ctx, const float* __restrict__ Wo, float* __restrict__ C) {
    const int m0 = blockIdx.y * 64, n0 = blockIdx.x * 64;
    f32x4 acc[4];
    gemm64x64<true>(Ctx, Wo, m0, n0, acc);
    const int lane = threadIdx.x & 63, wave = threadIdx.x >> 6;
    const int lrow = lane & 15, quad = lane >> 4;
    #pragma unroll
    for (int j = 0; j < 4; j++)
        #pragma unroll
        for (int i = 0; i < 4; i++) {
            int m = m0 + wave * 16 + quad * 4 + i;
            int n = n0 + j * 16 + lrow;
            C[m * DIM + n] = acc[j][i];
        }
}

// ---------------- residual + LayerNorm (all fp32) ----------------
__global__ __launch_bounds__(256) void ln_kernel(
        const float* __restrict__ C, const float* __restrict__ Xq,
        const float* __restrict__ gamma, const float* __restrict__ beta,
        float* __restrict__ out) {
    __shared__ float rbuf[4];
    const int m = blockIdx.x, tid = threadIdx.x;
    const float* crow = C + m * DIM;
    const float* xrow = Xq + m * DIM;
    float v[4]; float s = 0.f, s2 = 0.f;
    #pragma unroll
    for (int i = 0; i < 4; i++) {
        int d = tid + (i << 8);
        float x = crow[d] + xrow[d];
        v[i] = x; s += x; s2 += x * x;
    }
    float S  = block_reduce(s,  rbuf, 1);
    float S2 = block_reduce(s2, rbuf, 1);
    float mu  = S * (1.0f / DIM);
    float var = S2 * (1.0f / DIM) - mu * mu;
    float rstd = rsqrtf(var + 1e-5f);
    #pragma unroll
    for (int i = 0; i < 4; i++) {
        int d = tid + (i << 8);
        out[m * DIM + d] = (v[i] - mu) * rstd * gamma[d] + beta[d];
    }
}

extern "C" void kernel_launch(void* const* d_in, const int* in_sizes, int n_in,
                              void* d_out, int out_size, void* d_ws, size_t ws_size,
                              hipStream_t stream) {
    const float* Xq    = (const float*)d_in[0];
    const float* Xk    = (const float*)d_in[1];
    const float* Xv    = (const float*)d_in[2];
    const int*   mask  = (const int*)  d_in[3];
    const float* Wq    = (const float*)d_in[4];
    const float* Wk    = (const float*)d_in[5];
    const float* Wv    = (const float*)d_in[6];
    const float* Wo    = (const float*)d_in[7];
    const float* gamma = (const float*)d_in[8];
    const float* beta  = (const float*)d_in[9];
    float* out = (float*)d_out;

    // ws layout (32 MB): Qp[0,8M) Kp[8,16M) Vt[16,24M) Ctx[24,32M) all bf16;
    // C fp32 overlaps [0,16M) = Qp+Kp, which are dead once attention has run.
    char* ws = (char*)d_ws;
    bfraw* Qp  = (bfraw*)(ws);
    bfraw* Kp  = (bfraw*)(ws + (8u  << 20));
    bfraw* Vt  = (bfraw*)(ws + (16u << 20));
    bfraw* Ctx = (bfraw*)(ws + (24u << 20));
    float* C   = (float*)(ws);

    dim3 blk(256);
    qkv_gemm  <<<dim3(DIM / 64, MROWS / 64, 3), blk, 0, stream>>>(Xq, Xk, Xv, Wq, Wk, Wv, Qp, Kp, Vt);
    attn_flash<<<dim3(SEQ / 64, NH, BATCH),     blk, 0, stream>>>(Qp, Kp, Vt, mask, Ctx);
    out_gemm  <<<dim3(DIM / 64, MROWS / 64),    blk, 0, stream>>>(Ctx, Wo, C);
    ln_kernel <<<dim3(MROWS),                   blk, 0, stream>>>(C, Xq, gamma, beta, out);
}

// Round 4
// 267.608 us; speedup vs baseline: 26.7865x; 1.3178x over previous
//
#include <hip/hip_runtime.h>

#define NH    16
#define DK    64
#define DIM   1024
#define BATCH 2
#define SEQ   2048
#define MROWS (BATCH*SEQ)   // 4096
#define BK    32
#define QSCALE 0.18033688011112043f   // 0.125 * log2(e): folded into Q projection
#define SENT   -44.0f                 // sentinel in log2 domain; exp2(-44)=5.68e-14
#define PCONST 5.684341886080802e-14f // exp2(-44)

typedef unsigned short bfraw;
typedef __attribute__((ext_vector_type(8))) __bf16 bf16x8;
typedef __attribute__((ext_vector_type(8))) unsigned short u16x8;
typedef __attribute__((ext_vector_type(4))) float f32x4;

__device__ __forceinline__ float bf2f(bfraw u) {
    union { unsigned int i; float f; } x; x.i = ((unsigned int)u) << 16; return x.f;
}
__device__ __forceinline__ bfraw f2bf(float f) {          // RNE
    union { float f; unsigned int i; } x; x.f = f;
    unsigned int r = x.i + 0x7FFFu + ((x.i >> 16) & 1u);
    return (bfraw)(r >> 16);
}
__device__ __forceinline__ bfraw f2bf_trunc(float f) {    // truncate (P only; bias cancels in softmax normalize)
    union { float f; unsigned int i; } x; x.f = f;
    return (bfraw)(x.i >> 16);
}
__device__ __forceinline__ float fexp2(float x) {
#if __has_builtin(__builtin_amdgcn_exp2f)
    return __builtin_amdgcn_exp2f(x);
#else
    return exp2f(x);
#endif
}

// async global->LDS, 16B per lane; lds arg is the WAVE-uniform base (HW adds lane*16B)
__device__ __forceinline__ void gload16(const bfraw* g, bfraw* l) {
#if __has_builtin(__builtin_amdgcn_global_load_lds)
    __builtin_amdgcn_global_load_lds(
        (const __attribute__((address_space(1))) unsigned int*)g,
        (__attribute__((address_space(3))) unsigned int*)l, 16, 0, 0);
#else
    *(u16x8*)(l + (threadIdx.x & 63) * 8) = *(const u16x8*)g;
#endif
}

__device__ __forceinline__ float block_reduce(float val, float* rbuf, int op) {
    const int lane = threadIdx.x & 63, wave = threadIdx.x >> 6;
    #pragma unroll
    for (int off = 32; off; off >>= 1) {
        float o = __shfl_xor(val, off, 64);
        val = op ? (val + o) : fmaxf(val, o);
    }
    if (lane == 0) rbuf[wave] = val;
    __syncthreads();
    float r = op ? (rbuf[0] + rbuf[1] + rbuf[2] + rbuf[3])
                 : fmaxf(fmaxf(rbuf[0], rbuf[1]), fmaxf(rbuf[2], rbuf[3]));
    __syncthreads();
    return r;
}

// ---------------- fp32 -> bf16 convert pass ----------------
__global__ __launch_bounds__(256) void cvt_kernel(
        const float* __restrict__ x0, const float* __restrict__ x1, const float* __restrict__ x2,
        const float* __restrict__ w0, const float* __restrict__ w1, const float* __restrict__ w2,
        const float* __restrict__ w3, bfraw* __restrict__ Xb, bfraw* __restrict__ Wb) {
    const int t = blockIdx.y;
    const float* src; bfraw* dst; int n;
    if (t < 3) { src = (t == 0) ? x0 : (t == 1) ? x1 : x2; dst = Xb + t * (MROWS * DIM); n = MROWS * DIM; }
    else { int u = t - 3; src = (u == 0) ? w0 : (u == 1) ? w1 : (u == 2) ? w2 : w3;
           dst = Wb + u * (DIM * DIM); n = DIM * DIM; }
    int idx = (blockIdx.x * 256 + threadIdx.x) * 8;
    if (idx >= n) return;
    f32x4 a = *(const f32x4*)(src + idx);
    f32x4 b = *(const f32x4*)(src + idx + 4);
    u16x8 o;
    #pragma unroll
    for (int j = 0; j < 4; j++) { o[j] = f2bf(a[j]); o[4 + j] = f2bf(b[j]); }
    *(u16x8*)(dst + idx) = o;
}

// ---------------- 128x128 MFMA GEMM (m97 structure): C = A[M,K] * B[N,K]^T ----------------
// 256 threads = 4 waves (2x2); wave computes 64x64 = 4x4 MFMA tiles; BK=32.
__device__ __forceinline__ void gemm128(const bfraw* __restrict__ A, const bfraw* __restrict__ B,
                                        int m0, int n0, f32x4 acc[4][4]) {
    __shared__ __align__(16) bfraw As[128 * BK];
    __shared__ __align__(16) bfraw Bs[128 * BK];
    const int tid = threadIdx.x, wave = tid >> 6;
    const int lane = tid & 63, lrow = lane & 15, quad = lane >> 4;
    const int wy = wave >> 1, wx = wave & 1;
    const int sr = tid >> 2, sc8 = (tid & 3) << 3;     // staging row 0..63, k-col {0,8,16,24}
    const bfraw* ga0 = A + (m0 + sr) * DIM + sc8;
    const bfraw* ga1 = A + (m0 + 64 + sr) * DIM + sc8;
    const bfraw* gb0 = B + (n0 + sr) * DIM + sc8;
    const bfraw* gb1 = B + (n0 + 64 + sr) * DIM + sc8;
    bfraw* la = As + wave * 512;                        // elem offset; +2048 = rows 64..127
    bfraw* lb = Bs + wave * 512;

    #pragma unroll
    for (int i = 0; i < 4; i++)
        #pragma unroll
        for (int j = 0; j < 4; j++) { f32x4 z = {0.f, 0.f, 0.f, 0.f}; acc[i][j] = z; }

    for (int k0 = 0; k0 < DIM; k0 += BK) {
        __syncthreads();                                // prior iter's LDS reads done
        gload16(ga0 + k0, la);
        gload16(ga1 + k0, la + 2048);
        gload16(gb0 + k0, lb);
        gload16(gb1 + k0, lb + 2048);
        __syncthreads();                                // vmcnt drained by barrier
        bf16x8 af[4], bfg[4];
        #pragma unroll
        for (int mi = 0; mi < 4; mi++)
            af[mi] = *(const bf16x8*)&As[(wy * 64 + mi * 16 + lrow) * BK + quad * 8];
        #pragma unroll
        for (int ni = 0; ni < 4; ni++)
            bfg[ni] = *(const bf16x8*)&Bs[(wx * 64 + ni * 16 + lrow) * BK + quad * 8];
        #pragma unroll
        for (int mi = 0; mi < 4; mi++)
            #pragma unroll
            for (int ni = 0; ni < 4; ni++)
                acc[mi][ni] = __builtin_amdgcn_mfma_f32_16x16x32_bf16(af[mi], bfg[ni], acc[mi][ni], 0, 0, 0);
    }
}

// ---------------- QKV projection ----------------
// Q out scaled by QSCALE, [B,H,S,DK]; K out [B,H,S,DK]; V out transposed [B,H,DK,S].
__global__ __launch_bounds__(256) void qkv_gemm(
        const bfraw* __restrict__ Xb, const bfraw* __restrict__ Wb,
        bfraw* __restrict__ Qp, bfraw* __restrict__ Kp, bfraw* __restrict__ Vt) {
    const int which = blockIdx.z;
    const bfraw* A = Xb + which * (MROWS * DIM);
    const bfraw* B = Wb + which * (DIM * DIM);
    bfraw* O = (which == 0) ? Qp : (which == 1) ? Kp : Vt;
    const int m0 = blockIdx.y * 128, n0 = blockIdx.x * 128;
    f32x4 acc[4][4];
    gemm128(A, B, m0, n0, acc);
    const int lane = threadIdx.x & 63, wave = threadIdx.x >> 6;
    const int lrow = lane & 15, quad = lane >> 4;
    const int wy = wave >> 1, wx = wave & 1;
    const float scale = (which == 0) ? QSCALE : 1.0f;
    #pragma unroll
    for (int mi = 0; mi < 4; mi++)
        #pragma unroll
        for (int ni = 0; ni < 4; ni++)
            #pragma unroll
            for (int i = 0; i < 4; i++) {
                int m = m0 + wy * 64 + mi * 16 + quad * 4 + i;
                int n = n0 + wx * 64 + ni * 16 + lrow;
                int b = m >> 11, s = m & (SEQ - 1), h = n >> 6, kk = n & (DK - 1);
                bfraw v = f2bf(acc[mi][ni][i] * scale);
                if (which == 2) O[(((b * NH + h) * DK) + kk) * SEQ + s] = v;
                else            O[(((b * NH + h) * SEQ) + s) * DK + kk] = v;
            }
}

// ---------------- flash MFMA attention, no-max log2-domain softmax ----------------
// p = exp2(sc); invalid -> exp2(SENT) exactly (uniform for fully-masked rows, matching
// the reference's -1e12 semantics; 1e-13-relative noise otherwise). Tiles fully below
// the causal diagonal have constant P: PV-only with a splat A-frag, QK/softmax skipped.
__global__ __launch_bounds__(256) void attn_flash(
        const bfraw* __restrict__ Qp, const bfraw* __restrict__ Kp, const bfraw* __restrict__ Vt,
        const int* __restrict__ mask, bfraw* __restrict__ Ctx) {
    __shared__ __align__(16) bfraw Ks[64 * 72];
    __shared__ __align__(16) bfraw Vs[64 * 72];
    __shared__ __align__(16) bfraw Pw[4][16 * 68];     // stride 68: quads 8 banks apart
    __shared__ unsigned short Mk[SEQ];
    const int qt = blockIdx.x, h = blockIdx.y, b = blockIdx.z;
    const int tid = threadIdx.x, wave = tid >> 6, lane = tid & 63;
    const int lrow = lane & 15, quad = lane >> 4;
    const int baseK = ((b * NH + h) * SEQ) * DK;
    const int baseV = ((b * NH + h) * DK) * SEQ;
    const int qbase = qt * 64 + wave * 16;
    const int ldr = tid >> 2, ldc = (tid & 3) << 4;
    const int diagKt = qt * 64;

    for (int i = tid; i < SEQ; i += 256) Mk[i] = (unsigned short)(mask[b * SEQ + i] != 0);

    bf16x8 qf[2];
    qf[0] = *(const bf16x8*)(Qp + baseK + (qbase + lrow) * DK + quad * 8);
    qf[1] = *(const bf16x8*)(Qp + baseK + (qbase + lrow) * DK + 32 + quad * 8);

    f32x4 O[4]; float lsum[4];
    #pragma unroll
    for (int n = 0; n < 4; n++) { f32x4 z = {0.f, 0.f, 0.f, 0.f}; O[n] = z; }
    #pragma unroll
    for (int i = 0; i < 4; i++) lsum[i] = 0.f;

    union { u16x8 u; bf16x8 h; } pc;
    #pragma unroll
    for (int j = 0; j < 8; j++) pc.u[j] = f2bf_trunc(PCONST);
    const bf16x8 pa_c = pc.h;

    __syncthreads();                                    // Mk visible

    // ---- phase 1: tiles fully below diagonal (all scores = sentinel) ----
    for (int kt0 = 0; kt0 < diagKt; kt0 += 64) {
        u16x8 v0 = *(const u16x8*)(Vt + baseV + ldr * SEQ + kt0 + ldc);
        u16x8 v1 = *(const u16x8*)(Vt + baseV + ldr * SEQ + kt0 + ldc + 8);
        __syncthreads();
        *(u16x8*)&Vs[ldr * 72 + ldc]     = v0;
        *(u16x8*)&Vs[ldr * 72 + ldc + 8] = v1;
        __syncthreads();
        #pragma unroll
        for (int n = 0; n < 4; n++)
            #pragma unroll
            for (int ks = 0; ks < 2; ks++) {
                bf16x8 vb = *(const bf16x8*)&Vs[(n * 16 + lrow) * 72 + ks * 32 + quad * 8];
                O[n] = __builtin_amdgcn_mfma_f32_16x16x32_bf16(pa_c, vb, O[n], 0, 0, 0);
            }
    }

    // ---- phase 2: diagonal + future tiles ----
    for (int kt0 = diagKt; kt0 < SEQ; kt0 += 64) {
        u16x8 k0 = *(const u16x8*)(Kp + baseK + (kt0 + ldr) * DK + ldc);
        u16x8 k1 = *(const u16x8*)(Kp + baseK + (kt0 + ldr) * DK + ldc + 8);
        u16x8 v0 = *(const u16x8*)(Vt + baseV + ldr * SEQ + kt0 + ldc);
        u16x8 v1 = *(const u16x8*)(Vt + baseV + ldr * SEQ + kt0 + ldc + 8);
        __syncthreads();
        *(u16x8*)&Ks[ldr * 72 + ldc]     = k0;
        *(u16x8*)&Ks[ldr * 72 + ldc + 8] = k1;
        *(u16x8*)&Vs[ldr * 72 + ldc]     = v0;
        *(u16x8*)&Vs[ldr * 72 + ldc + 8] = v1;
        __syncthreads();

        f32x4 S[4];
        #pragma unroll
        for (int n = 0; n < 4; n++) {
            f32x4 z = {0.f, 0.f, 0.f, 0.f}; S[n] = z;
            #pragma unroll
            for (int ks = 0; ks < 2; ks++) {
                bf16x8 kb = *(const bf16x8*)&Ks[(n * 16 + lrow) * 72 + ks * 32 + quad * 8];
                S[n] = __builtin_amdgcn_mfma_f32_16x16x32_bf16(qf[ks], kb, S[n], 0, 0, 0);
            }
        }

        float p[4][4];
        if (kt0 == diagKt) {                            // diagonal tile: full causal compare
            #pragma unroll
            for (int n = 0; n < 4; n++) {
                int s = kt0 + n * 16 + lrow;
                bool mk = (Mk[s] != 0);
                #pragma unroll
                for (int i = 0; i < 4; i++) {
                    bool valid = mk && (s > qbase + quad * 4 + i);
                    p[n][i] = fexp2(valid ? S[n][i] : SENT);
                }
            }
        } else {                                        // strictly-future tile: padding mask only
            #pragma unroll
            for (int n = 0; n < 4; n++) {
                bool mk = (Mk[kt0 + n * 16 + lrow] != 0);
                #pragma unroll
                for (int i = 0; i < 4; i++) p[n][i] = fexp2(mk ? S[n][i] : SENT);
            }
        }

        #pragma unroll
        for (int i = 0; i < 4; i++) lsum[i] += (p[0][i] + p[1][i]) + (p[2][i] + p[3][i]);

        #pragma unroll
        for (int n = 0; n < 4; n++)
            #pragma unroll
            for (int i = 0; i < 4; i++)
                Pw[wave][(quad * 4 + i) * 68 + n * 16 + lrow] = f2bf_trunc(p[n][i]);

        bf16x8 pa0 = *(const bf16x8*)&Pw[wave][lrow * 68 + quad * 8];
        bf16x8 pa1 = *(const bf16x8*)&Pw[wave][lrow * 68 + 32 + quad * 8];
        #pragma unroll
        for (int n = 0; n < 4; n++)
            #pragma unroll
            for (int ks = 0; ks < 2; ks++) {
                bf16x8 vb = *(const bf16x8*)&Vs[(n * 16 + lrow) * 72 + ks * 32 + quad * 8];
                O[n] = __builtin_amdgcn_mfma_f32_16x16x32_bf16(ks ? pa1 : pa0, vb, O[n], 0, 0, 0);
            }
    }

    float inv[4];
    #pragma unroll
    for (int i = 0; i < 4; i++) {
        float r = lsum[i];
        #pragma unroll
        for (int off = 1; off < 16; off <<= 1) r += __shfl_xor(r, off, 64);
        inv[i] = 1.0f / (r + (float)diagKt * PCONST);
    }
    #pragma unroll
    for (int n = 0; n < 4; n++)
        #pragma unroll
        for (int i = 0; i < 4; i++)
            Ctx[(b * SEQ + qbase + quad * 4 + i) * DIM + h * DK + n * 16 + lrow] = f2bf(O[n][i] * inv[i]);
}

// ---------------- output projection ----------------
__global__ __launch_bounds__(256) void out_gemm(
        const bfraw* __restrict__ Ctx, const bfraw* __restrict__ WoB, float* __restrict__ C) {
    const int m0 = blockIdx.y * 128, n0 = blockIdx.x * 128;
    f32x4 acc[4][4];
    gemm128(Ctx, WoB, m0, n0, acc);
    const int lane = threadIdx.x & 63, wave = threadIdx.x >> 6;
    const int lrow = lane & 15, quad = lane >> 4;
    const int wy = wave >> 1, wx = wave & 1;
    #pragma unroll
    for (int mi = 0; mi < 4; mi++)
        #pragma unroll
        for (int ni = 0; ni < 4; ni++)
            #pragma unroll
            for (int i = 0; i < 4; i++) {
                int m = m0 + wy * 64 + mi * 16 + quad * 4 + i;
                int n = n0 + wx * 64 + ni * 16 + lrow;
                C[m * DIM + n] = acc[mi][ni][i];
            }
}

// ---------------- residual + LayerNorm (fp32) ----------------
__global__ __launch_bounds__(256) void ln_kernel(
        const float* __restrict__ C, const float* __restrict__ Xq,
        const float* __restrict__ gamma, const float* __restrict__ beta,
        float* __restrict__ out) {
    __shared__ float rbuf[4];
    const int m = blockIdx.x, tid = threadIdx.x;
    const float* crow = C + m * DIM;
    const float* xrow = Xq + m * DIM;
    float v[4]; float s = 0.f, s2 = 0.f;
    #pragma unroll
    for (int i = 0; i < 4; i++) {
        int d = tid + (i << 8);
        float x = crow[d] + xrow[d];
        v[i] = x; s += x; s2 += x * x;
    }
    float S  = block_reduce(s,  rbuf, 1);
    float S2 = block_reduce(s2, rbuf, 1);
    float mu  = S * (1.0f / DIM);
    float var = S2 * (1.0f / DIM) - mu * mu;
    float rstd = rsqrtf(var + 1e-5f);
    #pragma unroll
    for (int i = 0; i < 4; i++) {
        int d = tid + (i << 8);
        out[m * DIM + d] = (v[i] - mu) * rstd * gamma[d] + beta[d];
    }
}

extern "C" void kernel_launch(void* const* d_in, const int* in_sizes, int n_in,
                              void* d_out, int out_size, void* d_ws, size_t ws_size,
                              hipStream_t stream) {
    const float* Xq    = (const float*)d_in[0];
    const float* Xk    = (const float*)d_in[1];
    const float* Xv    = (const float*)d_in[2];
    const int*   mask  = (const int*)  d_in[3];
    const float* Wq    = (const float*)d_in[4];
    const float* Wk    = (const float*)d_in[5];
    const float* Wv    = (const float*)d_in[6];
    const float* Wo    = (const float*)d_in[7];
    const float* gamma = (const float*)d_in[8];
    const float* beta  = (const float*)d_in[9];
    float* out = (float*)d_out;

    // ws (64 MB): Xb bf16 [0,24M) | Wb bf16 [24,32M) | Qp [32,40) Kp [40,48) Vt [48,56) Ctx [56,64)
    // C fp32 [0,16M) overlaps Xb (dead after qkv_gemm).
    char* ws = (char*)d_ws;
    bfraw* Xb  = (bfraw*)(ws);
    bfraw* Wb  = (bfraw*)(ws + (24u << 20));
    bfraw* Qp  = (bfraw*)(ws + (32u << 20));
    bfraw* Kp  = (bfraw*)(ws + (40u << 20));
    bfraw* Vt  = (bfraw*)(ws + (48u << 20));
    bfraw* Ctx = (bfraw*)(ws + (56u << 20));
    float* C   = (float*)(ws);

    dim3 blk(256);
    cvt_kernel<<<dim3(MROWS * DIM / (256 * 8), 7), blk, 0, stream>>>(Xq, Xk, Xv, Wq, Wk, Wv, Wo, Xb, Wb);
    qkv_gemm  <<<dim3(DIM / 128, MROWS / 128, 3),  blk, 0, stream>>>(Xb, Wb, Qp, Kp, Vt);
    attn_flash<<<dim3(SEQ / 64, NH, BATCH),        blk, 0, stream>>>(Qp, Kp, Vt, mask, Ctx);
    out_gemm  <<<dim3(DIM / 128, MROWS / 128),     blk, 0, stream>>>(Ctx, Wb + 3 * (DIM * DIM), C);
    ln_kernel <<<dim3(MROWS),                      blk, 0, stream>>>(C, Xq, gamma, beta, out);
}

// Round 5
// 243.286 us; speedup vs baseline: 29.4644x; 1.1000x over previous
//
#include <hip/hip_runtime.h>

#define NH    16
#define DK    64
#define DIM   1024
#define BATCH 2
#define SEQ   2048
#define MROWS (BATCH*SEQ)   // 4096
#define BK    64
#define QSCALE 0.18033688011112043f   // 0.125 * log2(e): folded into Q projection
#define SENT   -44.0f                 // sentinel in log2 domain; exp2(-44)=5.68e-14
#define PCONST 5.684341886080802e-14f // exp2(-44)

typedef unsigned short bfraw;
typedef __attribute__((ext_vector_type(8))) __bf16 bf16x8;
typedef __attribute__((ext_vector_type(8))) unsigned short u16x8;
typedef __attribute__((ext_vector_type(4))) float f32x4;

__device__ __forceinline__ float bf2f(bfraw u) {
    union { unsigned int i; float f; } x; x.i = ((unsigned int)u) << 16; return x.f;
}
__device__ __forceinline__ bfraw f2bf(float f) {          // RNE
    union { float f; unsigned int i; } x; x.f = f;
    unsigned int r = x.i + 0x7FFFu + ((x.i >> 16) & 1u);
    return (bfraw)(r >> 16);
}
__device__ __forceinline__ bfraw f2bf_trunc(float f) {    // truncate (P only; bias cancels in normalize)
    union { float f; unsigned int i; } x; x.f = f;
    return (bfraw)(x.i >> 16);
}
__device__ __forceinline__ float fexp2(float x) {
#if __has_builtin(__builtin_amdgcn_exp2f)
    return __builtin_amdgcn_exp2f(x);
#else
    return exp2f(x);
#endif
}

// async global->LDS, 16B/lane; lds base is WAVE-uniform (HW adds lane*16B)
__device__ __forceinline__ void gload16(const bfraw* g, bfraw* l) {
#if __has_builtin(__builtin_amdgcn_global_load_lds)
    __builtin_amdgcn_global_load_lds(
        (const __attribute__((address_space(1))) unsigned int*)g,
        (__attribute__((address_space(3))) unsigned int*)l, 16, 0, 0);
#else
    *(u16x8*)(l + (threadIdx.x & 63) * 8) = *(const u16x8*)g;
#endif
}

__device__ __forceinline__ float block_reduce(float val, float* rbuf, int op) {
    const int lane = threadIdx.x & 63, wave = threadIdx.x >> 6;
    #pragma unroll
    for (int off = 32; off; off >>= 1) {
        float o = __shfl_xor(val, off, 64);
        val = op ? (val + o) : fmaxf(val, o);
    }
    if (lane == 0) rbuf[wave] = val;
    __syncthreads();
    float r = op ? (rbuf[0] + rbuf[1] + rbuf[2] + rbuf[3])
                 : fmaxf(fmaxf(rbuf[0], rbuf[1]), fmaxf(rbuf[2], rbuf[3]));
    __syncthreads();
    return r;
}

// ---------------- fp32 -> bf16 convert pass ----------------
__global__ __launch_bounds__(256) void cvt_kernel(
        const float* __restrict__ x0, const float* __restrict__ x1, const float* __restrict__ x2,
        const float* __restrict__ w0, const float* __restrict__ w1, const float* __restrict__ w2,
        const float* __restrict__ w3, bfraw* __restrict__ Xb, bfraw* __restrict__ Wb) {
    const int t = blockIdx.y;
    const float* src; bfraw* dst; int n;
    if (t < 3) { src = (t == 0) ? x0 : (t == 1) ? x1 : x2; dst = Xb + t * (MROWS * DIM); n = MROWS * DIM; }
    else { int u = t - 3; src = (u == 0) ? w0 : (u == 1) ? w1 : (u == 2) ? w2 : w3;
           dst = Wb + u * (DIM * DIM); n = DIM * DIM; }
    int idx = (blockIdx.x * 256 + threadIdx.x) * 8;
    if (idx >= n) return;
    f32x4 a = *(const f32x4*)(src + idx);
    f32x4 b = *(const f32x4*)(src + idx + 4);
    u16x8 o;
    #pragma unroll
    for (int j = 0; j < 4; j++) { o[j] = f2bf(a[j]); o[4 + j] = f2bf(b[j]); }
    *(u16x8*)(dst + idx) = o;
}

// ---------------- 128x128 MFMA GEMM, BK=64, XOR-swizzled LDS ----------------
// LDS element (row, chunk) holds global k-chunk (chunk ^ (row&7)); swizzle applied on the
// GLOBAL address so global_load_lds lane-contiguity is preserved. Fragment ds_read_b128
// phases then spread across all 32 banks (2-way = free).
__device__ __forceinline__ void gemm128(const bfraw* __restrict__ A, const bfraw* __restrict__ B,
                                        int m0, int n0, f32x4 acc[4][4]) {
    __shared__ __align__(16) bfraw As[128 * BK];   // 16 KB
    __shared__ __align__(16) bfraw Bs[128 * BK];   // 16 KB
    const int tid = threadIdx.x, wave = tid >> 6;
    const int lane = tid & 63, lrow = lane & 15, quad = lane >> 4;
    const int wy = wave >> 1, wx = wave & 1;
    const int swz = lrow & 7;
    const int srow = tid >> 3;                          // 0..31
    const int schunk = ((tid & 7) ^ (srow & 7)) << 3;   // swizzled k offset (elems)
    const bfraw* ga[4]; const bfraw* gb[4];
    #pragma unroll
    for (int g = 0; g < 4; g++) {
        ga[g] = A + (m0 + g * 32 + srow) * DIM + schunk;
        gb[g] = B + (n0 + g * 32 + srow) * DIM + schunk;
    }
    bfraw* la = As + wave * 512;    // wave-uniform dest bases
    bfraw* lb = Bs + wave * 512;

    #pragma unroll
    for (int i = 0; i < 4; i++)
        #pragma unroll
        for (int j = 0; j < 4; j++) { f32x4 z = {0.f, 0.f, 0.f, 0.f}; acc[i][j] = z; }

    for (int k0 = 0; k0 < DIM; k0 += BK) {
        __syncthreads();                                // prior iter's LDS reads done
        #pragma unroll
        for (int g = 0; g < 4; g++) gload16(ga[g] + k0, la + g * 2048);
        #pragma unroll
        for (int g = 0; g < 4; g++) gload16(gb[g] + k0, lb + g * 2048);
        __syncthreads();                                // barrier drains vmcnt
        #pragma unroll
        for (int ks = 0; ks < 2; ks++) {
            const int c = (ks << 2) | quad;
            bf16x8 af[4], bfg[4];
            #pragma unroll
            for (int mi = 0; mi < 4; mi++)
                af[mi] = *(const bf16x8*)&As[(wy * 64 + mi * 16 + lrow) * BK + ((c ^ swz) << 3)];
            #pragma unroll
            for (int ni = 0; ni < 4; ni++)
                bfg[ni] = *(const bf16x8*)&Bs[(wx * 64 + ni * 16 + lrow) * BK + ((c ^ swz) << 3)];
            #pragma unroll
            for (int mi = 0; mi < 4; mi++)
                #pragma unroll
                for (int ni = 0; ni < 4; ni++)
                    acc[mi][ni] = __builtin_amdgcn_mfma_f32_16x16x32_bf16(af[mi], bfg[ni], acc[mi][ni], 0, 0, 0);
        }
    }
}

// ---------------- QKV projection (grid: x=m-tiles for XCD locality) ----------------
__global__ __launch_bounds__(256) void qkv_gemm(
        const bfraw* __restrict__ Xb, const bfraw* __restrict__ Wb,
        bfraw* __restrict__ Qp, bfraw* __restrict__ Kp, bfraw* __restrict__ Vt) {
    const int which = blockIdx.z;
    const bfraw* A = Xb + which * (MROWS * DIM);
    const bfraw* B = Wb + which * (DIM * DIM);
    bfraw* O = (which == 0) ? Qp : (which == 1) ? Kp : Vt;
    const int m0 = blockIdx.x * 128, n0 = blockIdx.y * 128;
    f32x4 acc[4][4];
    gemm128(A, B, m0, n0, acc);
    const int lane = threadIdx.x & 63, wave = threadIdx.x >> 6;
    const int lrow = lane & 15, quad = lane >> 4;
    const int wy = wave >> 1, wx = wave & 1;
    const float scale = (which == 0) ? QSCALE : 1.0f;
    #pragma unroll
    for (int mi = 0; mi < 4; mi++)
        #pragma unroll
        for (int ni = 0; ni < 4; ni++)
            #pragma unroll
            for (int i = 0; i < 4; i++) {
                int m = m0 + wy * 64 + mi * 16 + quad * 4 + i;
                int n = n0 + wx * 64 + ni * 16 + lrow;
                int b = m >> 11, s = m & (SEQ - 1), h = n >> 6, kk = n & (DK - 1);
                bfraw v = f2bf(acc[mi][ni][i] * scale);
                if (which == 2) O[(((b * NH + h) * DK) + kk) * SEQ + s] = v;
                else            O[(((b * NH + h) * SEQ) + s) * DK + kk] = v;
            }
}

// ---------------- V tile-boundary prefix sums ----------------
// Scum[bh][qt][d] = sum_{s < qt*64} V[bh][d][s]  (fp32; one block per bh)
__global__ __launch_bounds__(256) void vsum_kernel(const bfraw* __restrict__ Vt,
                                                   float* __restrict__ Scum) {
    __shared__ float Ts[32][65];
    const int bh = blockIdx.x, tid = threadIdx.x;
    const int d = tid & 63, part = tid >> 6;
    const bfraw* vrow = Vt + (bh * DK + d) * SEQ;
    for (int qt = part * 8; qt < part * 8 + 8; qt++) {
        float s = 0.f;
        #pragma unroll
        for (int j = 0; j < 64; j += 8) {
            u16x8 v = *(const u16x8*)(vrow + qt * 64 + j);
            #pragma unroll
            for (int e = 0; e < 8; e++) s += bf2f(v[e]);
        }
        Ts[qt][d] = s;
    }
    __syncthreads();
    if (tid < 64) {
        float run = 0.f;
        for (int qt = 0; qt < 32; qt++) {
            Scum[(bh * 32 + qt) * 64 + tid] = run;
            run += Ts[qt][tid];
        }
    }
}

// ---------------- flash MFMA attention ----------------
// grid (bh=32, qt=32): linear%8 = bh%8 -> all q-tiles of one (b,h) share an XCD (K/V L2-resident).
// Below-diagonal contribution folded in analytically via Scum (uniform P = PCONST).
__global__ __launch_bounds__(256) void attn_flash(
        const bfraw* __restrict__ Qp, const bfraw* __restrict__ Kp, const bfraw* __restrict__ Vt,
        const float* __restrict__ Scum, const int* __restrict__ mask, bfraw* __restrict__ Ctx) {
    __shared__ __align__(16) bfraw Ks[64 * 72];
    __shared__ __align__(16) bfraw Vs[64 * 72];
    __shared__ __align__(16) bfraw Pw[4][16 * 68];
    __shared__ unsigned short Mk[SEQ];
    const int bh = blockIdx.x, qt = blockIdx.y;
    const int b = bh >> 4, h = bh & 15;
    const int tid = threadIdx.x, wave = tid >> 6, lane = tid & 63;
    const int lrow = lane & 15, quad = lane >> 4;
    const int baseK = ((b * NH + h) * SEQ) * DK;
    const int baseV = ((b * NH + h) * DK) * SEQ;
    const int qbase = qt * 64 + wave * 16;
    const int ldr = tid >> 2, ldc = (tid & 3) << 4;
    const int diagKt = qt * 64;

    for (int i = tid; i < SEQ; i += 256) Mk[i] = (unsigned short)(mask[b * SEQ + i] != 0);

    bf16x8 qf[2];
    qf[0] = *(const bf16x8*)(Qp + baseK + (qbase + lrow) * DK + quad * 8);
    qf[1] = *(const bf16x8*)(Qp + baseK + (qbase + lrow) * DK + 32 + quad * 8);

    f32x4 O[4]; float lsum[4];
    #pragma unroll
    for (int n = 0; n < 4; n++) {
        float base = PCONST * Scum[(bh * 32 + qt) * 64 + n * 16 + lrow];
        #pragma unroll
        for (int i = 0; i < 4; i++) O[n][i] = base;
    }
    #pragma unroll
    for (int i = 0; i < 4; i++) lsum[i] = 0.f;

    __syncthreads();                                    // Mk visible

    for (int kt0 = diagKt; kt0 < SEQ; kt0 += 64) {
        u16x8 k0 = *(const u16x8*)(Kp + baseK + (kt0 + ldr) * DK + ldc);
        u16x8 k1 = *(const u16x8*)(Kp + baseK + (kt0 + ldr) * DK + ldc + 8);
        u16x8 v0 = *(const u16x8*)(Vt + baseV + ldr * SEQ + kt0 + ldc);
        u16x8 v1 = *(const u16x8*)(Vt + baseV + ldr * SEQ + kt0 + ldc + 8);
        __syncthreads();
        *(u16x8*)&Ks[ldr * 72 + ldc]     = k0;
        *(u16x8*)&Ks[ldr * 72 + ldc + 8] = k1;
        *(u16x8*)&Vs[ldr * 72 + ldc]     = v0;
        *(u16x8*)&Vs[ldr * 72 + ldc + 8] = v1;
        __syncthreads();

        f32x4 S[4];
        #pragma unroll
        for (int n = 0; n < 4; n++) {
            f32x4 z = {0.f, 0.f, 0.f, 0.f}; S[n] = z;
            #pragma unroll
            for (int ks = 0; ks < 2; ks++) {
                bf16x8 kb = *(const bf16x8*)&Ks[(n * 16 + lrow) * 72 + ks * 32 + quad * 8];
                S[n] = __builtin_amdgcn_mfma_f32_16x16x32_bf16(qf[ks], kb, S[n], 0, 0, 0);
            }
        }

        float p[4][4];
        if (kt0 == diagKt) {                            // diagonal tile: full causal compare
            #pragma unroll
            for (int n = 0; n < 4; n++) {
                int s = kt0 + n * 16 + lrow;
                bool mk = (Mk[s] != 0);
                #pragma unroll
                for (int i = 0; i < 4; i++) {
                    bool valid = mk && (s > qbase + quad * 4 + i);
                    p[n][i] = fexp2(valid ? S[n][i] : SENT);
                }
            }
        } else {                                        // strictly-future: padding mask only
            #pragma unroll
            for (int n = 0; n < 4; n++) {
                bool mk = (Mk[kt0 + n * 16 + lrow] != 0);
                #pragma unroll
                for (int i = 0; i < 4; i++) p[n][i] = fexp2(mk ? S[n][i] : SENT);
            }
        }

        #pragma unroll
        for (int i = 0; i < 4; i++) lsum[i] += (p[0][i] + p[1][i]) + (p[2][i] + p[3][i]);

        #pragma unroll
        for (int n = 0; n < 4; n++)
            #pragma unroll
            for (int i = 0; i < 4; i++)
                Pw[wave][(quad * 4 + i) * 68 + n * 16 + lrow] = f2bf_trunc(p[n][i]);

        bf16x8 pa0 = *(const bf16x8*)&Pw[wave][lrow * 68 + quad * 8];
        bf16x8 pa1 = *(const bf16x8*)&Pw[wave][lrow * 68 + 32 + quad * 8];
        #pragma unroll
        for (int n = 0; n < 4; n++)
            #pragma unroll
            for (int ks = 0; ks < 2; ks++) {
                bf16x8 vb = *(const bf16x8*)&Vs[(n * 16 + lrow) * 72 + ks * 32 + quad * 8];
                O[n] = __builtin_amdgcn_mfma_f32_16x16x32_bf16(ks ? pa1 : pa0, vb, O[n], 0, 0, 0);
            }
    }

    float inv[4];
    #pragma unroll
    for (int i = 0; i < 4; i++) {
        float r = lsum[i];
        #pragma unroll
        for (int off = 1; off < 16; off <<= 1) r += __shfl_xor(r, off, 64);
        inv[i] = 1.0f / (r + (float)diagKt * PCONST);
    }
    #pragma unroll
    for (int n = 0; n < 4; n++)
        #pragma unroll
        for (int i = 0; i < 4; i++)
            Ctx[(b * SEQ + qbase + quad * 4 + i) * DIM + h * DK + n * 16 + lrow] = f2bf(O[n][i] * inv[i]);
}

// ---------------- output projection (grid: x=m-tiles) ----------------
__global__ __launch_bounds__(256) void out_gemm(
        const bfraw* __restrict__ Ctx, const bfraw* __restrict__ WoB, float* __restrict__ C) {
    const int m0 = blockIdx.x * 128, n0 = blockIdx.y * 128;
    f32x4 acc[4][4];
    gemm128(Ctx, WoB, m0, n0, acc);
    const int lane = threadIdx.x & 63, wave = threadIdx.x >> 6;
    const int lrow = lane & 15, quad = lane >> 4;
    const int wy = wave >> 1, wx = wave & 1;
    #pragma unroll
    for (int mi = 0; mi < 4; mi++)
        #pragma unroll
        for (int ni = 0; ni < 4; ni++)
            #pragma unroll
            for (int i = 0; i < 4; i++) {
                int m = m0 + wy * 64 + mi * 16 + quad * 4 + i;
                int n = n0 + wx * 64 + ni * 16 + lrow;
                C[m * DIM + n] = acc[mi][ni][i];
            }
}

// ---------------- residual + LayerNorm (fp32) ----------------
__global__ __launch_bounds__(256) void ln_kernel(
        const float* __restrict__ C, const float* __restrict__ Xq,
        const float* __restrict__ gamma, const float* __restrict__ beta,
        float* __restrict__ out) {
    __shared__ float rbuf[4];
    const int m = blockIdx.x, tid = threadIdx.x;
    const float* crow = C + m * DIM;
    const float* xrow = Xq + m * DIM;
    float v[4]; float s = 0.f, s2 = 0.f;
    #pragma unroll
    for (int i = 0; i < 4; i++) {
        int d = tid + (i << 8);
        float x = crow[d] + xrow[d];
        v[i] = x; s += x; s2 += x * x;
    }
    float S  = block_reduce(s,  rbuf, 1);
    float S2 = block_reduce(s2, rbuf, 1);
    float mu  = S * (1.0f / DIM);
    float var = S2 * (1.0f / DIM) - mu * mu;
    float rstd = rsqrtf(var + 1e-5f);
    #pragma unroll
    for (int i = 0; i < 4; i++) {
        int d = tid + (i << 8);
        out[m * DIM + d] = (v[i] - mu) * rstd * gamma[d] + beta[d];
    }
}

extern "C" void kernel_launch(void* const* d_in, const int* in_sizes, int n_in,
                              void* d_out, int out_size, void* d_ws, size_t ws_size,
                              hipStream_t stream) {
    const float* Xq    = (const float*)d_in[0];
    const float* Xk    = (const float*)d_in[1];
    const float* Xv    = (const float*)d_in[2];
    const int*   mask  = (const int*)  d_in[3];
    const float* Wq    = (const float*)d_in[4];
    const float* Wk    = (const float*)d_in[5];
    const float* Wv    = (const float*)d_in[6];
    const float* Wo    = (const float*)d_in[7];
    const float* gamma = (const float*)d_in[8];
    const float* beta  = (const float*)d_in[9];
    float* out = (float*)d_out;

    // ws (64 MB): Xb bf16 [0,24M) | Wb bf16 [24,32M) | Qp [32,40) Kp [40,48) Vt [48,56) Ctx [56,64)
    // C fp32 [0,16M) and Scum [16M,16.25M) overlap Xb (dead after qkv_gemm).
    char* ws = (char*)d_ws;
    bfraw* Xb   = (bfraw*)(ws);
    bfraw* Wb   = (bfraw*)(ws + (24u << 20));
    bfraw* Qp   = (bfraw*)(ws + (32u << 20));
    bfraw* Kp   = (bfraw*)(ws + (40u << 20));
    bfraw* Vt   = (bfraw*)(ws + (48u << 20));
    bfraw* Ctx  = (bfraw*)(ws + (56u << 20));
    float* C    = (float*)(ws);
    float* Scum = (float*)(ws + (16u << 20));

    dim3 blk(256);
    cvt_kernel<<<dim3(MROWS * DIM / (256 * 8), 7), blk, 0, stream>>>(Xq, Xk, Xv, Wq, Wk, Wv, Wo, Xb, Wb);
    qkv_gemm  <<<dim3(MROWS / 128, DIM / 128, 3),  blk, 0, stream>>>(Xb, Wb, Qp, Kp, Vt);
    vsum_kernel<<<dim3(BATCH * NH),                blk, 0, stream>>>(Vt, Scum);
    attn_flash<<<dim3(BATCH * NH, SEQ / 64),       blk, 0, stream>>>(Qp, Kp, Vt, Scum, mask, Ctx);
    out_gemm  <<<dim3(MROWS / 128, DIM / 128),     blk, 0, stream>>>(Ctx, Wb + 3 * (DIM * DIM), C);
    ln_kernel <<<dim3(MROWS),                      blk, 0, stream>>>(C, Xq, gamma, beta, out);
}